// Round 2
// baseline (405.877 us; speedup 1.0000x reference)
//
#include <hip/hip_runtime.h>
#include <hip/hip_bf16.h>
#include <math.h>

#define CIN 128
#define HH 128
#define WW 128
#define HWX (HH*WW)
#define COUT 256
#define NB 4

typedef __attribute__((ext_vector_type(8))) short short8;
typedef __attribute__((ext_vector_type(4))) float f32x4;
typedef __attribute__((ext_vector_type(2))) float f2v;
typedef __attribute__((ext_vector_type(8))) unsigned short ushort8;

__device__ __forceinline__ unsigned short f2bf(float f) {
    union { float f; unsigned int u; } c; c.f = f;
    unsigned int u = c.u + 0x7FFF + ((c.u >> 16) & 1);   // RNE
    return (unsigned short)(u >> 16);
}
__device__ __forceinline__ float bf2f(unsigned short u) {
    union { unsigned int u; float f; } c; c.u = ((unsigned int)u) << 16;
    return c.f;
}

// ---------------------------------------------------------------------------
// Prep 1: pack offset/mod conv weights contiguously: wofft[c][t][28]
// ---------------------------------------------------------------------------
__global__ __launch_bounds__(256) void wpack_kernel(
    const float* __restrict__ offw, const float* __restrict__ modw,
    float* __restrict__ wofft)
{
    int i = blockIdx.x * 256 + threadIdx.x;
    if (i >= CIN * 9 * 28) return;
    int o = i % 28;
    int t = (i / 28) % 9;
    int c = i / 252;
    float v = 0.f;
    if (o < 18)      v = offw[(o * CIN + c) * 9 + t];
    else if (o < 27) v = modw[((o - 18) * CIN + c) * 9 + t];
    wofft[i] = v;
}

// ---------------------------------------------------------------------------
// Prep 2: bf16 A-fragment image (layout verified R2-R4).
//   L = ((c36*16 + mt)*64 + l)*8 + j ; o = mt*16+(l&15); c = cc*32+(l>>4)*8+j
// ---------------------------------------------------------------------------
__global__ __launch_bounds__(256) void wimg_kernel(
    const float* __restrict__ wgt, unsigned short* __restrict__ wAi)
{
    int i = blockIdx.x * 256 + threadIdx.x;   // < 294912
    int j  = i & 7;
    int l  = (i >> 3) & 63;
    int mt = (i >> 9) & 15;
    int cc = (i >> 13) & 3;
    int kk = i >> 15;
    int o = mt * 16 + (l & 15);
    int c = cc * 32 + (l >> 4) * 8 + j;
    wAi[i] = f2bf(wgt[(o * CIN + c) * 9 + kk]);
}

// ---------------------------------------------------------------------------
// Prep 3: NCHW -> NHWC fp32 transpose of x.
//   xT[((b*128 + y)*128 + x)*128 + c]
// ---------------------------------------------------------------------------
__global__ __launch_bounds__(256) void xt_kernel(
    const float* __restrict__ x, float* __restrict__ xT)
{
    __shared__ float ls[32][132];
    const int tid = threadIdx.x;
    const int bz = blockIdx.x;                // b*512 + y*4 + cg
    const int cg = bz & 3;
    const int y  = (bz >> 2) & 127;
    const int b  = bz >> 9;
    {
        int c  = tid >> 3;                    // 0..31
        int x0 = (tid & 7) << 4;              // 0,16,..,112
        const float* src = x + (((size_t)(b * CIN + (cg << 5) + c)) << 14) + (y << 7) + x0;
#pragma unroll
        for (int k = 0; k < 4; ++k)
            *(f32x4*)&ls[c][x0 + 4 * k] = *(const f32x4*)(src + 4 * k);
    }
    __syncthreads();
    {
        int xc = tid >> 1;                    // 0..127
        int h  = tid & 1;                     // 16-ch half
        float v[16];
#pragma unroll
        for (int j = 0; j < 16; ++j) v[j] = ls[h * 16 + j][xc];
        float* dst = xT + ((((size_t)((b << 7) + y) << 7) + xc) << 7) + (cg << 5) + (h << 4);
#pragma unroll
        for (int k = 0; k < 4; ++k) {
            f32x4 t = { v[4 * k], v[4 * k + 1], v[4 * k + 2], v[4 * k + 3] };
            *(f32x4*)(dst + 4 * k) = t;
        }
    }
}

// ---------------------------------------------------------------------------
// Kernel A1: partial offset/mask conv, 16-channel chunks (8-way split).
// ---------------------------------------------------------------------------
__global__ __launch_bounds__(256) void convpart_kernel(
    const float* __restrict__ x, const float* __restrict__ wofft,
    unsigned short* __restrict__ part)
{
    __shared__ float xs[8][10][34];

    const int tid = threadIdx.x;
    const int lx = tid & 31, ly = tid >> 5;
    const int z = blockIdx.z;               // b*8 + chunk
    const int b = z >> 3, chunk = z & 7;
    const int cbase = chunk * 16;
    const int ty0 = blockIdx.y * 8;
    const int tx0 = blockIdx.x * 32;
    const int ho = ty0 + ly, wo = tx0 + lx;

    float acc[27];
#pragma unroll
    for (int o = 0; o < 27; ++o) acc[o] = 0.f;

#pragma unroll 1
    for (int c0 = 0; c0 < 16; c0 += 8) {
        for (int e = tid; e < 8 * 10 * 34; e += 256) {
            int c = e / 340;
            int rem = e - c * 340;
            int r = rem / 34;
            int col = rem - r * 34;
            int gy = ty0 + r - 1, gx = tx0 + col - 1;
            float v = 0.f;
            if (gy >= 0 && gy < HH && gx >= 0 && gx < WW)
                v = x[(((b * CIN) + (cbase + c0 + c)) << 14) + (gy << 7) + gx];
            xs[c][r][col] = v;
        }
        __syncthreads();

#pragma unroll 1
        for (int c = 0; c < 8; ++c) {
            float xv[3][3];
#pragma unroll
            for (int dy = 0; dy < 3; ++dy)
#pragma unroll
                for (int dx = 0; dx < 3; ++dx)
                    xv[dy][dx] = xs[c][ly + dy][lx + dx];
#pragma unroll
            for (int t = 0; t < 9; ++t) {
                const float* wp = wofft + ((cbase + c0 + c) * 9 + t) * 28;
                float xt = xv[t / 3][t % 3];
#pragma unroll
                for (int o = 0; o < 27; ++o)
                    acc[o] = fmaf(xt, wp[o], acc[o]);
            }
        }
        __syncthreads();
    }

    const int pix = (ho << 7) + wo;
    unsigned short* pp = part + ((z * 27) << 14) + pix;
#pragma unroll
    for (int o = 0; o < 27; ++o)
        pp[o << 14] = f2bf(acc[o]);
}

// ---------------------------------------------------------------------------
// Kernel A2: combine 8 partials + sampling-table epilogue.
// ---------------------------------------------------------------------------
__global__ __launch_bounds__(256) void tables_kernel(
    const unsigned short* __restrict__ part, const float* __restrict__ offb,
    const float* __restrict__ modb,
    unsigned int* __restrict__ pk_out, float4* __restrict__ w4_out)
{
    const int gid = blockIdx.x * 256 + threadIdx.x;
    const int pix = gid & 16383;
    const int t = gid >> 14;                // b*9 + kk
    const int kk = t % 9;
    const int b = t / 9;
    const int ho = pix >> 7, wo = pix & 127;

    float oy = 0.f, ox = 0.f, mt = 0.f;
#pragma unroll
    for (int ch = 0; ch < 8; ++ch) {
        const unsigned short* pp = part + (((b * 8 + ch) * 27) << 14) + pix;
        oy += bf2f(pp[(2 * kk) << 14]);
        ox += bf2f(pp[(2 * kk + 1) << 14]);
        mt += bf2f(pp[(18 + kk) << 14]);
    }
    oy += offb[2 * kk];
    ox += offb[2 * kk + 1];
    mt += modb[kk];

    float m = 2.f / (1.f + expf(-mt));
    float py = (float)(ho - 1 + kk / 3) + oy;
    float px = (float)(wo - 1 + kk % 3) + ox;
    float y0f = floorf(py), x0f = floorf(px);
    float wy = py - y0f, wx = px - x0f;
    int y0 = (int)y0f, x0 = (int)x0f;
    int y1 = y0 + 1, x1 = x0 + 1;
    float vy0 = (y0 >= 0 && y0 < HH) ? 1.f : 0.f;
    float vy1 = (y1 >= 0 && y1 < HH) ? 1.f : 0.f;
    float vx0 = (x0 >= 0 && x0 < WW) ? 1.f : 0.f;
    float vx1 = (x1 >= 0 && x1 < WW) ? 1.f : 0.f;
    float a  = m * (1.f - wy) * vy0;
    float bb = m * wy * vy1;
    float u  = (1.f - wx) * vx0;
    float vv = wx * vx1;
    int y0c = min(max(y0, 0), HH - 1), y1c = min(max(y1, 0), HH - 1);
    int x0c = min(max(x0, 0), WW - 1), x1c = min(max(x1, 0), WW - 1);
    int cb = min(max(x0, 0), WW - 2);
    float wl = ((x0c == cb) ? u : 0.f) + ((x1c == cb) ? vv : 0.f);
    float wr = ((x0c == cb + 1) ? u : 0.f) + ((x1c == cb + 1) ? vv : 0.f);
    unsigned int pkv = (unsigned)y0c | ((unsigned)y1c << 7) |
                       ((unsigned)cb << 14);
    pk_out[gid] = pkv;
    w4_out[gid] = make_float4(a * wl, a * wr, bb * wl, bb * wr);
}

// ---------------------------------------------------------------------------
// Kernel G: gather/im2col from NHWC xT -> fragment-ready bf16.
// R2 changes: (1) samp stores are NON-TEMPORAL -- the 19 MB/XCD write stream
// was evicting the ~4.3 MB xT band from L2, pushing all reads to the
// Infinity Cache (~10 TB/s observed ceiling). (2) ci hand-unrolled so all
// 16 dwordx4 loads issue before one drain (2x MLP vs 8-load+drain twice).
// ---------------------------------------------------------------------------
__global__ __launch_bounds__(256) void gather_kernel(
    const float* __restrict__ xT, const unsigned int* __restrict__ pk,
    const float4* __restrict__ w4, unsigned short* __restrict__ samp,
    int b0, int nb2)
{
    const int tid = threadIdx.x;
    const int wave = tid >> 6;
    const int l = tid & 63;
    const int F = blockIdx.x;
    const int band = F % nb2;               // nb2 = nb*2 bands
    const int s = F / nb2;                  // 0..255
    const int lb = band >> 1;
    const int b = b0 + lb;
    const int yh = band & 1;
    const int unit = s * 4 + wave;          // 0..1023
    const int cchalf = unit & 1;
    const int gb = unit >> 1;               // 0..511
    const int row = yh * 64 + (gb >> 3);
    const int gx16 = gb & 7;
    const int pix = (row << 7) + (gx16 << 4) + (l & 15);
    const int g = (lb << 10) + (row << 3) + gx16;
    const int q = l >> 4;
    const float* xb = xT + ((size_t)b << 21);
    unsigned short* sg = samp + (((size_t)g * 36) << 9) + (l << 3);
    const int chq = (cchalf << 6) + (q << 3);   // base channel: cchalf*64 + q*8

    int gi = ((b * 9) << 14) + pix;
    unsigned int pkv = pk[gi];
    float4 wv = w4[gi];

#pragma unroll 1
    for (int kk = 0; kk < 9; ++kk) {
        // prefetch next kk's table entries (clamped: no OOB at kk==8)
        int gin = gi + ((kk < 8) ? 16384 : 0);
        unsigned int pkn = pk[gin];
        float4 wvn = w4[gin];

        const int y0c = pkv & 127;
        const int y1c = (pkv >> 7) & 127;
        const int cb  = pkv >> 14;               // in [0,126]
        const float* p00 = xb + ((((y0c << 7) + cb) << 7) + chq);
        const float* p10 = xb + ((((y1c << 7) + cb) << 7) + chq);

        // ---- issue all 16 loads back-to-back (ci=0 then ci=1) ----
        f32x4 A00a = *(const f32x4*)(p00);
        f32x4 A00b = *(const f32x4*)(p00 + 4);
        f32x4 A01a = *(const f32x4*)(p00 + 128);   // col cb+1 = +512 B
        f32x4 A01b = *(const f32x4*)(p00 + 132);
        f32x4 A10a = *(const f32x4*)(p10);
        f32x4 A10b = *(const f32x4*)(p10 + 4);
        f32x4 A11a = *(const f32x4*)(p10 + 128);
        f32x4 A11b = *(const f32x4*)(p10 + 132);
        f32x4 B00a = *(const f32x4*)(p00 + 32);
        f32x4 B00b = *(const f32x4*)(p00 + 36);
        f32x4 B01a = *(const f32x4*)(p00 + 160);
        f32x4 B01b = *(const f32x4*)(p00 + 164);
        f32x4 B10a = *(const f32x4*)(p10 + 32);
        f32x4 B10b = *(const f32x4*)(p10 + 36);
        f32x4 B11a = *(const f32x4*)(p10 + 160);
        f32x4 B11b = *(const f32x4*)(p10 + 164);

        unsigned short v[8];
#pragma unroll
        for (int j = 0; j < 4; ++j)
            v[j] = f2bf(wv.x * A00a[j] + wv.y * A01a[j] +
                        wv.z * A10a[j] + wv.w * A11a[j]);
#pragma unroll
        for (int j = 0; j < 4; ++j)
            v[4 + j] = f2bf(wv.x * A00b[j] + wv.y * A01b[j] +
                            wv.z * A10b[j] + wv.w * A11b[j]);
        {
            ushort8 pkd = {v[0], v[1], v[2], v[3], v[4], v[5], v[6], v[7]};
            const int cc = (cchalf << 1);
            __builtin_nontemporal_store(pkd, (ushort8*)&sg[((kk << 2) + cc) << 9]);
        }
#pragma unroll
        for (int j = 0; j < 4; ++j)
            v[j] = f2bf(wv.x * B00a[j] + wv.y * B01a[j] +
                        wv.z * B10a[j] + wv.w * B11a[j]);
#pragma unroll
        for (int j = 0; j < 4; ++j)
            v[4 + j] = f2bf(wv.x * B00b[j] + wv.y * B01b[j] +
                            wv.z * B10b[j] + wv.w * B11b[j]);
        {
            ushort8 pkd = {v[0], v[1], v[2], v[3], v[4], v[5], v[6], v[7]};
            const int cc = (cchalf << 1) + 1;
            __builtin_nontemporal_store(pkd, (ushort8*)&sg[((kk << 2) + cc) << 9]);
        }

        pkv = pkn; wv = wvn;
        gi += 16384;
    }
}

// ---------------------------------------------------------------------------
// Kernel B: clean MFMA GEMM, both operands fragment-ready & contiguous.
// R2: samp (B operand) loads + out stores are non-temporal -- both are
// touched exactly once; keeps L2 for the reused wAi image.
// ---------------------------------------------------------------------------
__global__ __launch_bounds__(256) void dgemm_kernel(
    const unsigned short* __restrict__ wAi,
    const unsigned short* __restrict__ samp,
    float* __restrict__ out, int b0)
{
    const int tid = threadIdx.x;
    const int wave = tid >> 6;
    const int l = tid & 63;
    const int bx = blockIdx.x;
    const int lb = bx >> 8;
    const int b = b0 + lb;
    const int seg = bx & 255;
    const int pix0 = seg << 6;
    const unsigned short* sb =
        samp + (((size_t)((lb << 10) + (seg << 2)) * 36) << 9) + (l << 3);
    const int NTS = 36 << 9;                // nt stride in shorts

    f32x4 acc[4][4];
#pragma unroll
    for (int i = 0; i < 4; ++i)
#pragma unroll
        for (int j = 0; j < 4; ++j) acc[i][j] = (f32x4){0.f, 0.f, 0.f, 0.f};

    short8 bf[4], bfn[4];
#pragma unroll
    for (int nt = 0; nt < 4; ++nt)
        bf[nt] = __builtin_nontemporal_load((const short8*)(sb + nt * NTS));

#pragma unroll 1
    for (int c36 = 0; c36 < 36; ++c36) {
        // A fragments (oldest in vmcnt order)
        const unsigned short* ap = wAi + (c36 << 13) + (wave << 11) + (l << 3);
        short8 af[4];
#pragma unroll
        for (int mt = 0; mt < 4; ++mt)
            af[mt] = *(const short8*)(ap + (mt << 9));

        // prefetch next chunk's B (stays in flight across MFMAs)
        int cn = (c36 < 35) ? c36 + 1 : 35;
#pragma unroll
        for (int nt = 0; nt < 4; ++nt)
            bfn[nt] = __builtin_nontemporal_load(
                (const short8*)(sb + nt * NTS + (cn << 9)));

#pragma unroll
        for (int mt = 0; mt < 4; ++mt)
#pragma unroll
            for (int nt = 0; nt < 4; ++nt)
                acc[mt][nt] = __builtin_amdgcn_mfma_f32_16x16x32_bf16(
                    af[mt], bf[nt], acc[mt][nt], 0, 0, 0);

#pragma unroll
        for (int nt = 0; nt < 4; ++nt) bf[nt] = bfn[nt];
    }

    // epilogue: C/D col=lane&15 (=px), row=(lane>>4)*4+reg (verified R2-R4)
    const int crow = (l >> 4) * 4;
    const int pxl = pix0 + (l & 15);
#pragma unroll
    for (int mt = 0; mt < 4; ++mt) {
#pragma unroll
        for (int nt = 0; nt < 4; ++nt) {
#pragma unroll
            for (int r = 0; r < 4; ++r) {
                int o = wave * 64 + mt * 16 + crow + r;
                __builtin_nontemporal_store(acc[mt][nt][r],
                    &out[(((size_t)(b * COUT + o)) << 14) + pxl + nt * 16]);
            }
        }
    }
}

// ---------------------------------------------------------------------------
extern "C" void kernel_launch(void* const* d_in, const int* in_sizes, int n_in,
                              void* d_out, int out_size, void* d_ws, size_t ws_size,
                              hipStream_t stream)
{
    const float* x    = (const float*)d_in[0];
    const float* offw = (const float*)d_in[1];
    const float* offb = (const float*)d_in[2];
    const float* modw = (const float*)d_in[3];
    const float* modb = (const float*)d_in[4];
    const float* wgt  = (const float*)d_in[5];
    float* out = (float*)d_out;

    char* wsb = (char*)d_ws;
    unsigned int*   pkp   = (unsigned int*)wsb;                    //  2,359,296 B
    float4*         w4p   = (float4*)(wsb + 2359296);              //  9,437,184 B
    unsigned short* wAi   = (unsigned short*)(wsb + 11796480);     //    589,824 B
    float*          wofft = (float*)(wsb + 12386304);              //    129,024 B
    float*          xTp   = (float*)(wsb + 12515328);              // 33,554,432 B (persistent NHWC image)
    const size_t persistX = 12515328 + 33554432;                   // 46,069,760
    unsigned short* part  = (unsigned short*)(wsb + persistX);     // 28,311,552 B
    unsigned short* samp  = (unsigned short*)(wsb + persistX);     // reuses part region
    const size_t SAMP1 = 37748736;   // bytes per batch of samp

    // pick largest batch-group that fits: samp overlaps dead part buffer
    int nb = 4;
    if (ws_size < persistX + 4 * SAMP1) nb = 2;
    if (ws_size < persistX + 2 * SAMP1) nb = 1;
    // conv phase needs persistX + 28.3MB <= persistX + 1*SAMP1

    wpack_kernel<<<dim3((CIN * 9 * 28 + 255) / 256), 256, 0, stream>>>(offw, modw, wofft);
    wimg_kernel<<<dim3(COUT * CIN * 9 / 256), 256, 0, stream>>>(wgt, wAi);
    xt_kernel<<<dim3(NB * 128 * 4), 256, 0, stream>>>(x, xTp);
    convpart_kernel<<<dim3(WW / 32, HH / 8, NB * 8), 256, 0, stream>>>(x, wofft, part);
    tables_kernel<<<dim3(NB * 9 * HWX / 256), 256, 0, stream>>>(part, offb, modb, pkp, w4p);

    for (int b0 = 0; b0 < NB; b0 += nb) {
        gather_kernel<<<dim3(nb * 512), 256, 0, stream>>>(
            xTp, pkp, w4p, samp, b0, nb * 2);
        dgemm_kernel<<<dim3(nb * 256), 256, 0, stream>>>(wAi, samp, out, b0);
    }
}

// Round 4
// 317.667 us; speedup vs baseline: 1.2777x; 1.2777x over previous
//
#include <hip/hip_runtime.h>
#include <hip/hip_bf16.h>
#include <math.h>

#define CIN 128
#define HH 128
#define WW 128
#define HWX (HH*WW)
#define COUT 256
#define NB 4

typedef __attribute__((ext_vector_type(8))) short short8;
typedef __attribute__((ext_vector_type(4))) float f32x4;
typedef __attribute__((ext_vector_type(8))) unsigned short ushort8;

__device__ __forceinline__ unsigned short f2bf(float f) {
    union { float f; unsigned int u; } c; c.f = f;
    unsigned int u = c.u + 0x7FFF + ((c.u >> 16) & 1);   // RNE
    return (unsigned short)(u >> 16);
}
__device__ __forceinline__ float bf2f(unsigned short u) {
    union { unsigned int u; float f; } c; c.u = ((unsigned int)u) << 16;
    return c.f;
}

// ---------------------------------------------------------------------------
// Prep 1: pack offset/mod conv weights contiguously: wofft[c][t][28]
// ---------------------------------------------------------------------------
__global__ __launch_bounds__(256) void wpack_kernel(
    const float* __restrict__ offw, const float* __restrict__ modw,
    float* __restrict__ wofft)
{
    int i = blockIdx.x * 256 + threadIdx.x;
    if (i >= CIN * 9 * 28) return;
    int o = i % 28;
    int t = (i / 28) % 9;
    int c = i / 252;
    float v = 0.f;
    if (o < 18)      v = offw[(o * CIN + c) * 9 + t];
    else if (o < 27) v = modw[((o - 18) * CIN + c) * 9 + t];
    wofft[i] = v;
}

// ---------------------------------------------------------------------------
// Prep 2: bf16 A-fragment image (layout verified R2-R4).
//   L = ((c36*16 + mt)*64 + l)*8 + j ; o = mt*16+(l&15); c = cc*32+(l>>4)*8+j
// ---------------------------------------------------------------------------
__global__ __launch_bounds__(256) void wimg_kernel(
    const float* __restrict__ wgt, unsigned short* __restrict__ wAi)
{
    int i = blockIdx.x * 256 + threadIdx.x;   // < 294912
    int j  = i & 7;
    int l  = (i >> 3) & 63;
    int mt = (i >> 9) & 15;
    int cc = (i >> 13) & 3;
    int kk = i >> 15;
    int o = mt * 16 + (l & 15);
    int c = cc * 32 + (l >> 4) * 8 + j;
    wAi[i] = f2bf(wgt[(o * CIN + c) * 9 + kk]);
}

// ---------------------------------------------------------------------------
// Prep 3: NCHW -> NHWC fp32 transpose of x.
//   xT[((b*128 + y)*128 + x)*128 + c]
// ---------------------------------------------------------------------------
__global__ __launch_bounds__(256) void xt_kernel(
    const float* __restrict__ x, float* __restrict__ xT)
{
    __shared__ float ls[32][132];
    const int tid = threadIdx.x;
    const int bz = blockIdx.x;                // b*512 + y*4 + cg
    const int cg = bz & 3;
    const int y  = (bz >> 2) & 127;
    const int b  = bz >> 9;
    {
        int c  = tid >> 3;                    // 0..31
        int x0 = (tid & 7) << 4;              // 0,16,..,112
        const float* src = x + (((size_t)(b * CIN + (cg << 5) + c)) << 14) + (y << 7) + x0;
#pragma unroll
        for (int k = 0; k < 4; ++k)
            *(f32x4*)&ls[c][x0 + 4 * k] = *(const f32x4*)(src + 4 * k);
    }
    __syncthreads();
    {
        int xc = tid >> 1;                    // 0..127
        int h  = tid & 1;                     // 16-ch half
        float v[16];
#pragma unroll
        for (int j = 0; j < 16; ++j) v[j] = ls[h * 16 + j][xc];
        float* dst = xT + ((((size_t)((b << 7) + y) << 7) + xc) << 7) + (cg << 5) + (h << 4);
#pragma unroll
        for (int k = 0; k < 4; ++k) {
            f32x4 t = { v[4 * k], v[4 * k + 1], v[4 * k + 2], v[4 * k + 3] };
            *(f32x4*)(dst + 4 * k) = t;
        }
    }
}

// ---------------------------------------------------------------------------
// Kernel A1: partial offset/mask conv, 16-channel chunks (8-way split).
// ---------------------------------------------------------------------------
__global__ __launch_bounds__(256) void convpart_kernel(
    const float* __restrict__ x, const float* __restrict__ wofft,
    unsigned short* __restrict__ part)
{
    __shared__ float xs[8][10][34];

    const int tid = threadIdx.x;
    const int lx = tid & 31, ly = tid >> 5;
    const int z = blockIdx.z;               // b*8 + chunk
    const int b = z >> 3, chunk = z & 7;
    const int cbase = chunk * 16;
    const int ty0 = blockIdx.y * 8;
    const int tx0 = blockIdx.x * 32;
    const int ho = ty0 + ly, wo = tx0 + lx;

    float acc[27];
#pragma unroll
    for (int o = 0; o < 27; ++o) acc[o] = 0.f;

#pragma unroll 1
    for (int c0 = 0; c0 < 16; c0 += 8) {
        for (int e = tid; e < 8 * 10 * 34; e += 256) {
            int c = e / 340;
            int rem = e - c * 340;
            int r = rem / 34;
            int col = rem - r * 34;
            int gy = ty0 + r - 1, gx = tx0 + col - 1;
            float v = 0.f;
            if (gy >= 0 && gy < HH && gx >= 0 && gx < WW)
                v = x[(((b * CIN) + (cbase + c0 + c)) << 14) + (gy << 7) + gx];
            xs[c][r][col] = v;
        }
        __syncthreads();

#pragma unroll 1
        for (int c = 0; c < 8; ++c) {
            float xv[3][3];
#pragma unroll
            for (int dy = 0; dy < 3; ++dy)
#pragma unroll
                for (int dx = 0; dx < 3; ++dx)
                    xv[dy][dx] = xs[c][ly + dy][lx + dx];
#pragma unroll
            for (int t = 0; t < 9; ++t) {
                const float* wp = wofft + ((cbase + c0 + c) * 9 + t) * 28;
                float xt = xv[t / 3][t % 3];
#pragma unroll
                for (int o = 0; o < 27; ++o)
                    acc[o] = fmaf(xt, wp[o], acc[o]);
            }
        }
        __syncthreads();
    }

    const int pix = (ho << 7) + wo;
    unsigned short* pp = part + ((z * 27) << 14) + pix;
#pragma unroll
    for (int o = 0; o < 27; ++o)
        pp[o << 14] = f2bf(acc[o]);
}

// ---------------------------------------------------------------------------
// Kernel A2: combine 8 partials + sampling-table epilogue.
// ---------------------------------------------------------------------------
__global__ __launch_bounds__(256) void tables_kernel(
    const unsigned short* __restrict__ part, const float* __restrict__ offb,
    const float* __restrict__ modb,
    unsigned int* __restrict__ pk_out, float4* __restrict__ w4_out)
{
    const int gid = blockIdx.x * 256 + threadIdx.x;
    const int pix = gid & 16383;
    const int t = gid >> 14;                // b*9 + kk
    const int kk = t % 9;
    const int b = t / 9;
    const int ho = pix >> 7, wo = pix & 127;

    float oy = 0.f, ox = 0.f, mt = 0.f;
#pragma unroll
    for (int ch = 0; ch < 8; ++ch) {
        const unsigned short* pp = part + (((b * 8 + ch) * 27) << 14) + pix;
        oy += bf2f(pp[(2 * kk) << 14]);
        ox += bf2f(pp[(2 * kk + 1) << 14]);
        mt += bf2f(pp[(18 + kk) << 14]);
    }
    oy += offb[2 * kk];
    ox += offb[2 * kk + 1];
    mt += modb[kk];

    float m = 2.f / (1.f + expf(-mt));
    float py = (float)(ho - 1 + kk / 3) + oy;
    float px = (float)(wo - 1 + kk % 3) + ox;
    float y0f = floorf(py), x0f = floorf(px);
    float wy = py - y0f, wx = px - x0f;
    int y0 = (int)y0f, x0 = (int)x0f;
    int y1 = y0 + 1, x1 = x0 + 1;
    float vy0 = (y0 >= 0 && y0 < HH) ? 1.f : 0.f;
    float vy1 = (y1 >= 0 && y1 < HH) ? 1.f : 0.f;
    float vx0 = (x0 >= 0 && x0 < WW) ? 1.f : 0.f;
    float vx1 = (x1 >= 0 && x1 < WW) ? 1.f : 0.f;
    float a  = m * (1.f - wy) * vy0;
    float bb = m * wy * vy1;
    float u  = (1.f - wx) * vx0;
    float vv = wx * vx1;
    int y0c = min(max(y0, 0), HH - 1), y1c = min(max(y1, 0), HH - 1);
    int x0c = min(max(x0, 0), WW - 1), x1c = min(max(x1, 0), WW - 1);
    int cb = min(max(x0, 0), WW - 2);
    float wl = ((x0c == cb) ? u : 0.f) + ((x1c == cb) ? vv : 0.f);
    float wr = ((x0c == cb + 1) ? u : 0.f) + ((x1c == cb + 1) ? vv : 0.f);
    unsigned int pkv = (unsigned)y0c | ((unsigned)y1c << 7) |
                       ((unsigned)cb << 14);
    pk_out[gid] = pkv;
    w4_out[gid] = make_float4(a * wl, a * wr, bb * wl, bb * wr);
}

// ---------------------------------------------------------------------------
// Kernel G (R4 = R3 resubmit after infra failure): ideal-pattern gather.
// R2 diagnosis: 16 instrs x 32 scattered lines/wave/kk = 512 line-requests
// x 8192 waves x 9 kk x ~2cyc/line / 256 CU = 123 us ~= measured 131 us ->
// TA unique-line serialization bound. Fix: wave loads ONE pixel-corner-row
// (y, cb..cb+1, ch0..127) = 1024 B contiguous per instr (lane i -> base+16i,
// the ideal pattern; 16 lines fully consumed). 8 loads per 4-px step.
// Column blend via per-lane colf fma; column-sum via shfl_xor(32); repack
// 4ch-quads -> 8ch ushort8 fragments through 1KB wave-private LDS (no
// barriers, wave-synchronous). Stores line-coalesced (4 lanes/64B line).
// ---------------------------------------------------------------------------
__global__ __launch_bounds__(256) void gather_kernel(
    const float* __restrict__ xT, const unsigned int* __restrict__ pk,
    const float4* __restrict__ w4, unsigned short* __restrict__ samp,
    int b0, int nb2)
{
    __shared__ unsigned char glds[4096];      // 4 waves x 1 KB
    const int tid = threadIdx.x;
    const int wave = tid >> 6;
    const int l = tid & 63;
    unsigned char* wb = glds + (wave << 10);

    const int F = blockIdx.x;
    const int band = F % nb2;                 // nb2 = nb*2 bands (XCD-aligned)
    const int s = F / nb2;                    // 0..255
    const int lb = band >> 1;
    const int b = b0 + lb;
    const int yh = band & 1;
    const int unit = s * 4 + wave;            // 0..1023
    const int h = unit & 1;                   // pixel-half of the 16-px group
    const int gb = unit >> 1;                 // 0..511
    const int row = yh * 64 + (gb >> 3);
    const int gx16 = gb & 7;
    const int g = (lb << 10) + (row << 3) + gx16;
    const float* xb = xT + ((size_t)b << 21);
    unsigned short* sg0 = samp + (((size_t)g * 36) << 9);
    const float colf = (l >= 32) ? 1.f : 0.f;

    // lane (l&7) holds the sampling table entry for its pixel of this wave's 8
    int gi = ((b * 9) << 14) + (row << 7) + (gx16 << 4) + (h << 3) + (l & 7);
    unsigned int tpk = pk[gi];
    float4 tw = w4[gi];

#pragma unroll 1
    for (int kk = 0; kk < 9; ++kk) {
        // prefetch next kk's tables (clamped at kk==8)
        int gin = gi + ((kk < 8) ? 16384 : 0);
        unsigned int tpkn = pk[gin];
        float4 twn = w4[gin];

#pragma unroll
        for (int st = 0; st < 2; ++st) {
            f32x4 r0[4], r1[4];
            float cw0[4], cw1[4];
#pragma unroll
            for (int p = 0; p < 4; ++p) {
                const int idx = st * 4 + p;
                unsigned int pv = __shfl(tpk, idx);
                float wx_ = __shfl(tw.x, idx);
                float wy_ = __shfl(tw.y, idx);
                float wz_ = __shfl(tw.z, idx);
                float ww_ = __shfl(tw.w, idx);
                cw0[p] = fmaf(wy_ - wx_, colf, wx_);   // row y0 col weight
                cw1[p] = fmaf(ww_ - wz_, colf, wz_);   // row y1 col weight
                const int y0c = pv & 127;
                const int y1c = (pv >> 7) & 127;
                const int cb  = pv >> 14;              // [0,126]
                // 1024 B contiguous: cols cb, cb+1 x 128 ch; lane l -> 16 B
                const float* base0 = xb + ((((y0c << 7) + cb) << 7) + (l << 2));
                const float* base1 = xb + ((((y1c << 7) + cb) << 7) + (l << 2));
                r0[p] = *(const f32x4*)base0;
                r1[p] = *(const f32x4*)base1;
            }
#pragma unroll
            for (int p = 0; p < 4; ++p) {
                float res[4];
#pragma unroll
                for (int j = 0; j < 4; ++j) {
                    float t = r0[p][j] * cw0[p] + r1[p][j] * cw1[p];
                    res[j] = t + __shfl_xor(t, 32);    // add other column
                }
                unsigned int d0 = (unsigned int)f2bf(res[0]) |
                                  ((unsigned int)f2bf(res[1]) << 16);
                unsigned int d1 = (unsigned int)f2bf(res[2]) |
                                  ((unsigned int)f2bf(res[3]) << 16);
                uint2 dd; dd.x = d0; dd.y = d1;
                // lanes l and l+32 hold identical data; both write same bytes
                *(uint2*)(wb + (p << 8) + ((l & 31) << 3)) = dd;
            }
            // wave-synchronous repack: quad (l&31) -> octet chunks
            ushort8 chunk = *(ushort8*)(wb + ((l >> 4) << 8) + ((l & 15) << 4));
            const int px = (h << 3) + (st << 2) + (l >> 4); // pixel in group
            const int cc = (l & 15) >> 2;
            const int q  = l & 3;
            *(ushort8*)&sg0[((((kk << 2) + cc) << 6) + (q << 4) + px) << 3] =
                chunk;
        }
        tpk = tpkn; tw = twn;
        gi += 16384;
    }
}

// ---------------------------------------------------------------------------
// Kernel B: clean MFMA GEMM (R1 version restored -- NT loads/stores reverted,
// they evicted samp from L2 and cost +45 us in R2).
// ---------------------------------------------------------------------------
__global__ __launch_bounds__(256) void dgemm_kernel(
    const unsigned short* __restrict__ wAi,
    const unsigned short* __restrict__ samp,
    float* __restrict__ out, int b0)
{
    const int tid = threadIdx.x;
    const int wave = tid >> 6;
    const int l = tid & 63;
    const int bx = blockIdx.x;
    const int lb = bx >> 8;
    const int b = b0 + lb;
    const int seg = bx & 255;
    const int pix0 = seg << 6;
    const unsigned short* sb =
        samp + (((size_t)((lb << 10) + (seg << 2)) * 36) << 9) + (l << 3);
    const int NTS = 36 << 9;                // nt stride in shorts

    f32x4 acc[4][4];
#pragma unroll
    for (int i = 0; i < 4; ++i)
#pragma unroll
        for (int j = 0; j < 4; ++j) acc[i][j] = (f32x4){0.f, 0.f, 0.f, 0.f};

    short8 bf[4], bfn[4];
#pragma unroll
    for (int nt = 0; nt < 4; ++nt)
        bf[nt] = *(const short8*)(sb + nt * NTS);

#pragma unroll 1
    for (int c36 = 0; c36 < 36; ++c36) {
        // A fragments (oldest in vmcnt order)
        const unsigned short* ap = wAi + (c36 << 13) + (wave << 11) + (l << 3);
        short8 af[4];
#pragma unroll
        for (int mt = 0; mt < 4; ++mt)
            af[mt] = *(const short8*)(ap + (mt << 9));

        // prefetch next chunk's B (stays in flight across MFMAs)
        int cn = (c36 < 35) ? c36 + 1 : 35;
#pragma unroll
        for (int nt = 0; nt < 4; ++nt)
            bfn[nt] = *(const short8*)(sb + nt * NTS + (cn << 9));

#pragma unroll
        for (int mt = 0; mt < 4; ++mt)
#pragma unroll
            for (int nt = 0; nt < 4; ++nt)
                acc[mt][nt] = __builtin_amdgcn_mfma_f32_16x16x32_bf16(
                    af[mt], bf[nt], acc[mt][nt], 0, 0, 0);

#pragma unroll
        for (int nt = 0; nt < 4; ++nt) bf[nt] = bfn[nt];
    }

    // epilogue: C/D col=lane&15 (=px), row=(lane>>4)*4+reg (verified R2-R4)
    const int crow = (l >> 4) * 4;
    const int pxl = pix0 + (l & 15);
#pragma unroll
    for (int mt = 0; mt < 4; ++mt) {
#pragma unroll
        for (int nt = 0; nt < 4; ++nt) {
#pragma unroll
            for (int r = 0; r < 4; ++r) {
                int o = wave * 64 + mt * 16 + crow + r;
                out[(((size_t)(b * COUT + o)) << 14) + pxl + nt * 16] =
                    acc[mt][nt][r];
            }
        }
    }
}

// ---------------------------------------------------------------------------
extern "C" void kernel_launch(void* const* d_in, const int* in_sizes, int n_in,
                              void* d_out, int out_size, void* d_ws, size_t ws_size,
                              hipStream_t stream)
{
    const float* x    = (const float*)d_in[0];
    const float* offw = (const float*)d_in[1];
    const float* offb = (const float*)d_in[2];
    const float* modw = (const float*)d_in[3];
    const float* modb = (const float*)d_in[4];
    const float* wgt  = (const float*)d_in[5];
    float* out = (float*)d_out;

    char* wsb = (char*)d_ws;
    unsigned int*   pkp   = (unsigned int*)wsb;                    //  2,359,296 B
    float4*         w4p   = (float4*)(wsb + 2359296);              //  9,437,184 B
    unsigned short* wAi   = (unsigned short*)(wsb + 11796480);     //    589,824 B
    float*          wofft = (float*)(wsb + 12386304);              //    129,024 B
    float*          xTp   = (float*)(wsb + 12515328);              // 33,554,432 B (persistent NHWC image)
    const size_t persistX = 12515328 + 33554432;                   // 46,069,760
    unsigned short* part  = (unsigned short*)(wsb + persistX);     // 28,311,552 B
    unsigned short* samp  = (unsigned short*)(wsb + persistX);     // reuses part region
    const size_t SAMP1 = 37748736;   // bytes per batch of samp

    // pick largest batch-group that fits: samp overlaps dead part buffer
    int nb = 4;
    if (ws_size < persistX + 4 * SAMP1) nb = 2;
    if (ws_size < persistX + 2 * SAMP1) nb = 1;
    // conv phase needs persistX + 28.3MB <= persistX + 1*SAMP1

    wpack_kernel<<<dim3((CIN * 9 * 28 + 255) / 256), 256, 0, stream>>>(offw, modw, wofft);
    wimg_kernel<<<dim3(COUT * CIN * 9 / 256), 256, 0, stream>>>(wgt, wAi);
    xt_kernel<<<dim3(NB * 128 * 4), 256, 0, stream>>>(x, xTp);
    convpart_kernel<<<dim3(WW / 32, HH / 8, NB * 8), 256, 0, stream>>>(x, wofft, part);
    tables_kernel<<<dim3(NB * 9 * HWX / 256), 256, 0, stream>>>(part, offb, modb, pkp, w4p);

    for (int b0 = 0; b0 < NB; b0 += nb) {
        gather_kernel<<<dim3(nb * 512), 256, 0, stream>>>(
            xTp, pkp, w4p, samp, b0, nb * 2);
        dgemm_kernel<<<dim3(nb * 256), 256, 0, stream>>>(wAi, samp, out, b0);
    }
}